// Round 3
// baseline (477.132 us; speedup 1.0000x reference)
//
#include <hip/hip_runtime.h>

#define WAVE 64

// ---------------- degree count ----------------
__global__ void k_deg(const int* __restrict__ eu, const int* __restrict__ ei,
                      int nE, int nU, int* __restrict__ cnt) {
    int e = blockIdx.x * blockDim.x + threadIdx.x;
    if (e < nE) {
        atomicAdd(&cnt[eu[e]], 1);
        atomicAdd(&cnt[nU + ei[e]], 1);
    }
}

// ---------------- inv sqrt of degree (for z0 = D^-1/2 x0) ----------------
__global__ void k_inv(const int* __restrict__ cnt, float* __restrict__ inv, int N) {
    int n = blockIdx.x * blockDim.x + threadIdx.x;
    if (n < N) {
        int c = cnt[n];
        inv[n] = (c > 0) ? (1.0f / sqrtf((float)c)) : 0.0f;
    }
}

// ---------------- scan phase A: per-block sums (block=256) ----------------
__global__ void k_blocksum(const int* __restrict__ cnt, int N, int* __restrict__ bsum) {
    int i = blockIdx.x * 256 + threadIdx.x;
    int v = (i < N) ? cnt[i] : 0;
    #pragma unroll
    for (int o = 32; o > 0; o >>= 1) v += __shfl_down(v, o, WAVE);
    __shared__ int ws[4];
    if ((threadIdx.x & 63) == 0) ws[threadIdx.x >> 6] = v;
    __syncthreads();
    if (threadIdx.x == 0) bsum[blockIdx.x] = ws[0] + ws[1] + ws[2] + ws[3];
}

// ---------------- scan phase B: single-block exclusive scan of block sums ----------------
__global__ void k_scanbsum(int* __restrict__ bsum, int nB) {
    __shared__ int s[1024];
    int t = threadIdx.x;
    int v = (t < nB) ? bsum[t] : 0;
    s[t] = v;
    __syncthreads();
    for (int o = 1; o < 1024; o <<= 1) {
        int x = (t >= o) ? s[t - o] : 0;
        __syncthreads();
        s[t] += x;
        __syncthreads();
    }
    if (t < nB) bsum[t] = s[t] - v;  // exclusive
}

// ---------------- scan phase C: final exclusive positions -> row_ptr & cursor ----------------
__global__ void k_scanfinal(const int* __restrict__ cnt, const int* __restrict__ bsum,
                            int N, int* __restrict__ row_ptr, int* __restrict__ cursor) {
    int i = blockIdx.x * 256 + threadIdx.x;
    int v = (i < N) ? cnt[i] : 0;
    int lane = threadIdx.x & 63, wid = threadIdx.x >> 6;
    int inc = v;
    #pragma unroll
    for (int o = 1; o < WAVE; o <<= 1) {
        int x = __shfl_up(inc, o, WAVE);
        if (lane >= o) inc += x;
    }
    __shared__ int wsum[4];
    if (lane == 63) wsum[wid] = inc;
    __syncthreads();
    int woff = 0;
    for (int w2 = 0; w2 < wid; w2++) woff += wsum[w2];
    int excl = inc - v + woff + bsum[blockIdx.x];
    if (i < N) { row_ptr[i] = excl; cursor[i] = excl; }
    if (i == N - 1) row_ptr[N] = excl + v;
}

// ---------------- CSR scatter: col only (4B/entry halves dirty-line writeback) ----
__global__ void k_scatter(const int* __restrict__ eu, const int* __restrict__ ei,
                          int nE, int nU, int* __restrict__ cursor,
                          int* __restrict__ col) {
    int e = blockIdx.x * blockDim.x + threadIdx.x;
    if (e >= nE) return;
    int u = eu[e];
    int v = nU + ei[e];
    int p1 = atomicAdd(&cursor[v], 1); col[p1] = u;
    int p2 = atomicAdd(&cursor[u], 1); col[p2] = v;
}

// ---------------- z0 = inv .* concat(user_emb, item_emb), vectorized ----------------
__global__ void k_initz(const float4* __restrict__ ue, const float4* __restrict__ ie,
                        const float* __restrict__ inv,
                        int nU4, int nTot4, float4* __restrict__ z) {
    int i = blockIdx.x * blockDim.x + threadIdx.x;
    if (i >= nTot4) return;
    float4 v = (i < nU4) ? ue[i] : ie[i - nU4];
    float s = inv[i >> 4];
    v.x *= s; v.y *= s; v.z *= s; v.w *= s;
    z[i] = v;
}

// ---------------- layer-0 batch accumulate: read x0 straight from inputs ----------
__global__ void k_bacc0(const int* __restrict__ users, const int* __restrict__ items,
                        int B, const float* __restrict__ ue, const float* __restrict__ ie,
                        float* __restrict__ acc) {
    int b = blockIdx.x * (blockDim.x >> 6) + (threadIdx.x >> 6);
    int lane = threadIdx.x & 63;
    if (b >= 2 * B) return;
    const float* src = (b < B) ? (ue + (size_t)users[b] * 64)
                               : (ie + (size_t)items[b - B] * 64);
    acc[(size_t)b * 64 + lane] = src[lane];
}

// ---------------- layer-l batch accumulate: x_l = sqrt(deg) * z_l at batch rows ----
__global__ void k_baccl(const int* __restrict__ users, const int* __restrict__ items,
                        int B, int nU, const int* __restrict__ cnt,
                        const float* __restrict__ z, float* __restrict__ acc) {
    int b = blockIdx.x * (blockDim.x >> 6) + (threadIdx.x >> 6);
    int lane = threadIdx.x & 63;
    if (b >= 2 * B) return;
    int row = (b < B) ? users[b] : (nU + items[b - B]);
    float f = sqrtf((float)cnt[row]);
    acc[(size_t)b * 64 + lane] += f * z[(size_t)row * 64 + lane];
}

// ---------------- SPMM: z_out[r] = (1/deg r) * sum_{c in N(r)} z_in[c] -------------
// wave = one row; lane = 16*eidx + f4; 4 edge slots x 2-deep unroll = 8 gathers in flight
__global__ void k_spmm(const int* __restrict__ row_ptr, const int* __restrict__ col,
                       const float* __restrict__ x, float* __restrict__ y, int N) {
    int row = blockIdx.x * (blockDim.x >> 6) + (threadIdx.x >> 6);
    int lane = threadIdx.x & 63;
    int eidx = lane >> 4;
    int f4   = lane & 15;
    if (row >= N) return;
    int s = row_ptr[row], e = row_ptr[row + 1];
    float4 a0 = make_float4(0.f, 0.f, 0.f, 0.f);
    float4 a1 = make_float4(0.f, 0.f, 0.f, 0.f);
    int j = s + eidx;
    for (; j + 4 < e; j += 8) {
        int c0 = col[j];
        int c1 = col[j + 4];
        float4 v0 = ((const float4*)(x + (size_t)c0 * 64))[f4];
        float4 v1 = ((const float4*)(x + (size_t)c1 * 64))[f4];
        a0.x += v0.x; a0.y += v0.y; a0.z += v0.z; a0.w += v0.w;
        a1.x += v1.x; a1.y += v1.y; a1.z += v1.z; a1.w += v1.w;
    }
    if (j < e) {
        int c = col[j];
        float4 v = ((const float4*)(x + (size_t)c * 64))[f4];
        a0.x += v.x; a0.y += v.y; a0.z += v.z; a0.w += v.w;
    }
    a0.x += a1.x; a0.y += a1.y; a0.z += a1.z; a0.w += a1.w;
    #pragma unroll
    for (int o = 16; o <= 32; o <<= 1) {
        a0.x += __shfl_xor(a0.x, o, WAVE);
        a0.y += __shfl_xor(a0.y, o, WAVE);
        a0.z += __shfl_xor(a0.z, o, WAVE);
        a0.w += __shfl_xor(a0.w, o, WAVE);
    }
    if (eidx == 0) {
        float rdeg = (e > s) ? (1.0f / (float)(e - s)) : 0.0f;
        a0.x *= rdeg; a0.y *= rdeg; a0.z *= rdeg; a0.w *= rdeg;
        ((float4*)(y + (size_t)row * 64))[f4] = a0;
    }
}

// ---------------- final: gamma[b] = dot(acc_u[b], acc_i[b]) / 25 ----------------
__global__ void k_dot(const float* __restrict__ acc, int B, float* __restrict__ out) {
    int b = blockIdx.x * (blockDim.x >> 6) + (threadIdx.x >> 6);
    int lane = threadIdx.x & 63;
    if (b >= B) return;
    float p = acc[(size_t)b * 64 + lane] * acc[(size_t)(b + B) * 64 + lane];
    #pragma unroll
    for (int o = 32; o > 0; o >>= 1) p += __shfl_down(p, o, WAVE);
    if (lane == 0) out[b] = p * (1.0f / 25.0f);
}

extern "C" void kernel_launch(void* const* d_in, const int* in_sizes, int n_in,
                              void* d_out, int out_size, void* d_ws, size_t ws_size,
                              hipStream_t stream) {
    const int*   users = (const int*)d_in[0];
    const int*   items = (const int*)d_in[1];
    const int*   eu    = (const int*)d_in[2];
    const int*   ei    = (const int*)d_in[3];
    const float* ue    = (const float*)d_in[4];
    const float* ie    = (const float*)d_in[5];
    float* out = (float*)d_out;

    const int D  = 64;
    const int B  = in_sizes[0];
    const int nE = in_sizes[2];
    const int nU = in_sizes[4] / D;
    const int nI = in_sizes[5] / D;
    const int N  = nU + nI;

    // ---- carve workspace (256B-aligned chunks) ----
    char* p = (char*)d_ws;
    auto alloc = [&](size_t bytes) -> void* {
        void* r = (void*)p;
        p += (bytes + 255) & ~(size_t)255;
        return r;
    };
    int*   cnt     = (int*)  alloc((size_t)N * 4);
    int*   row_ptr = (int*)  alloc((size_t)(N + 1) * 4);
    int*   cursor  = (int*)  alloc((size_t)N * 4);
    float* inv     = (float*)alloc((size_t)N * 4);
    int*   col     = (int*)  alloc((size_t)2 * nE * 4);
    float* za      = (float*)alloc((size_t)N * D * 4);
    float* zb      = (float*)alloc((size_t)N * D * 4);
    float* acc     = (float*)alloc((size_t)2 * B * D * 4);
    int*   bsum    = (int*)  alloc(4096);  // up to 1024 block sums

    const int nB = (N + 255) / 256;  // 586 for N=150000; must be <= 1024

    // ---- build CSR (col only; normalization folded into z-space iteration) ----
    hipMemsetAsync(cnt, 0, (size_t)N * 4, stream);
    k_deg<<<(nE + 255) / 256, 256, 0, stream>>>(eu, ei, nE, nU, cnt);
    k_inv<<<(N + 255) / 256, 256, 0, stream>>>(cnt, inv, N);
    k_blocksum<<<nB, 256, 0, stream>>>(cnt, N, bsum);
    k_scanbsum<<<1, 1024, 0, stream>>>(bsum, nB);
    k_scanfinal<<<nB, 256, 0, stream>>>(cnt, bsum, N, row_ptr, cursor);
    k_scatter<<<(nE + 255) / 256, 256, 0, stream>>>(eu, ei, nE, nU, cursor, col);

    // ---- z0 and layer-0 batch accumulate ----
    int nTot4 = N * (D / 4);
    k_initz<<<(nTot4 + 255) / 256, 256, 0, stream>>>(
        (const float4*)ue, (const float4*)ie, inv, nU * (D / 4), nTot4, (float4*)za);
    k_bacc0<<<(2 * B + 3) / 4, 256, 0, stream>>>(users, items, B, ue, ie, acc);

    // ---- 4 propagation layers in z-space: z_{l+1} = D^-1 A z_l ----
    float* zin = za;
    float* zout = zb;
    for (int l = 0; l < 4; l++) {
        k_spmm<<<(N + 3) / 4, 256, 0, stream>>>(row_ptr, col, zin, zout, N);
        k_baccl<<<(2 * B + 3) / 4, 256, 0, stream>>>(users, items, B, nU, cnt, zout, acc);
        float* t = zin; zin = zout; zout = t;
    }

    // ---- final dot ----
    k_dot<<<(B + 3) / 4, 256, 0, stream>>>(acc, B, out);
}